// Round 6
// baseline (253.291 us; speedup 1.0000x reference)
//
#include <hip/hip_runtime.h>
#include <hip/hip_fp16.h>

#define NB 2048
#define NC 8
#define NT 1024
#define EPS 1e-5f
#define SLOPE (1.0f/128.0f)
#define NELEM (2048.0f*1024.0f)
#define TB (NT*NB)

// ---- ws layout ----
// floats [0,1024)      : bn1 partials, 64 slots x 16
// floats [1024,2048)   : bn2 partials, 32 slots x 32
// floats [9216,10240)  : folded params (fp32 + packed-half2-as-uint)
// byte 65536           : xT  fp16 [T][B][8]     (32 MiB)
// byte 65536+32MiB     : pre fp16 [11][T][B]    (44 MiB planes)
#define PAR_OFF 9216
// fp32 (index into par float array)
#define PF_S4  0
#define PF_O4  8
#define PF_B1F 16
#define PF_B2F 40
#define PF_B3F 56
// packed half2 (index into (unsigned*)par)
#define PU_A4   96
#define PU_W1   128
#define PU_W2   224
#define PU_W3X  416
#define PU_W3F  460
#define PU_W3L  504
#define PU_W3FF 548
#define XT_BYTE  65536
#define PWS_BYTE (65536 + 2048*1024*8*2)

typedef _Float16 h2 __attribute__((ext_vector_type(2)));
typedef __fp16  fp16v2 __attribute__((ext_vector_type(2)));
union U32H2 { unsigned u; h2 h; fp16v2 f; unsigned short us[2]; };

__device__ __forceinline__ float leaky(float z){ return fmaxf(z, z*SLOPE); }
__device__ __forceinline__ unsigned short f2h(float v){ return __half_as_ushort(__float2half(v)); }
__device__ __forceinline__ float h2f(unsigned short u){ return __half2float(__ushort_as_half(u)); }
__device__ __forceinline__ h2 uph2(unsigned u){ U32H2 x; x.u = u; return x.h; }
__device__ __forceinline__ h2 pk(float a, float b){
    U32H2 x; x.f = __builtin_amdgcn_cvt_pkrtz(a, b); return x.h;   // v_cvt_pkrtz_f16_f32
}

#if defined(__has_builtin)
#if __has_builtin(__builtin_amdgcn_fdot2)
#define HAVE_FDOT2 1
#endif
#endif
#ifdef HAVE_FDOT2
__device__ __forceinline__ float fdot2(h2 a, h2 b, float c){ return __builtin_amdgcn_fdot2(a, b, c, false); }
#else
__device__ __forceinline__ float fdot2(h2 a, h2 b, float c){
    return c + (float)a[0]*(float)b[0] + (float)a[1]*(float)b[1];
}
#endif

// ---------------- K0: BN1 stats + transpose x -> xT[t][b][8] fp16 ----------------
__global__ __launch_bounds__(256) void k0_tr(const float* __restrict__ x,
                                             unsigned short* __restrict__ xT,
                                             float* __restrict__ ws)
{
    __shared__ unsigned short tile[64*134];
    __shared__ float sred[4][4][2];
    const int tid = threadIdx.x;
    const int bg = blockIdx.x >> 4;
    const int tg = blockIdx.x & 15;
    const int b0 = bg*16, t0 = tg*64;
    float s = 0.f, s2 = 0.f;
#pragma unroll
    for(int r=0;r<8;r++){
        const int flat4 = r*256 + tid;
        const int row = flat4 >> 4;          // 0..127 = b*8+c
        const int t4  = flat4 & 15;
        const int b = row >> 3, c = row & 7;
        float4 v = *(const float4*)(x + (size_t)(b0+b)*8192 + c*1024 + t0 + t4*4);
        s  += v.x+v.y+v.z+v.w;
        s2 += v.x*v.x+v.y*v.y+v.z*v.z+v.w*v.w;
        const int base = b*8 + c;
        tile[(t4*4+0)*134 + base] = f2h(v.x);
        tile[(t4*4+1)*134 + base] = f2h(v.y);
        tile[(t4*4+2)*134 + base] = f2h(v.z);
        tile[(t4*4+3)*134 + base] = f2h(v.w);
    }
    // per-thread c is constant within 16-lane groups
#pragma unroll
    for(int m=8;m>=1;m>>=1){ s += __shfl_xor(s,m,64); s2 += __shfl_xor(s2,m,64); }
    const int lane = tid & 63, wave = tid >> 6;
    if((lane & 15) == 0){ sred[wave][lane>>4][0] = s; sred[wave][lane>>4][1] = s2; }
    __syncthreads();
    if(tid < 16){
        const int c = tid & 7, which = tid >> 3;
        const int w0 = (c < 4) ? 0 : 1, g = c & 3;
        const float v = sred[w0][g][which] + sred[w0+2][g][which];
        atomicAdd(&ws[(blockIdx.x & 63)*16 + which*8 + c], v);
    }
#pragma unroll
    for(int r=0;r<8;r++){
        const int q = r*256 + tid;
        const int t = q >> 5, inner = q & 31;
        const unsigned int lo = *(const unsigned int*)&tile[t*134 + inner*4];
        const unsigned int hi = *(const unsigned int*)&tile[t*134 + inner*4 + 2];
        *(uint2*)(xT + ((size_t)(t0+t)*NB + b0)*8 + inner*4) = make_uint2(lo, hi);
    }
}

// ---------------- K2: finalize BN1, fold + pack all weights ----------------
__device__ __forceinline__ unsigned pk2u(float a, float b){
    U32H2 v; v.us[0] = f2h(a); v.us[1] = f2h(b); return v.u;
}
__global__ __launch_bounds__(256) void k2_fold(const float* __restrict__ g1, const float* __restrict__ bb1,
    const float* __restrict__ w1, const float* __restrict__ b1,
    const float* __restrict__ w2, const float* __restrict__ b2,
    const float* __restrict__ w3, const float* __restrict__ b3,
    const float* __restrict__ A, float* __restrict__ ws)
{
    float* par = ws + PAR_OFF;
    unsigned* paru = (unsigned*)par;
    __shared__ float st[16];
    __shared__ float wred[4][16];
    __shared__ float sc[8], oc[8];
    const int tid = threadIdx.x;
    // parallel stats read: 1024 floats, 4 coalesced loads/thread, shuffle-combine
    {
        float v = ws[tid] + ws[256+tid] + ws[512+tid] + ws[768+tid];  // slots {s,s+16,s+32,s+48}, cnt=tid&15
        v += __shfl_xor(v, 16, 64);
        v += __shfl_xor(v, 32, 64);
        const int lane = tid & 63, wave = tid >> 6;
        if(lane < 16) wred[wave][lane] = v;
    }
    __syncthreads();
    if(tid < 16) st[tid] = wred[0][tid]+wred[1][tid]+wred[2][tid]+wred[3][tid];
    __syncthreads();
    if(tid<8){
        const float inv = 1.0f/NELEM;
        float m  = st[tid]*inv;
        float v  = st[8+tid]*inv - m*m;
        float s_ = g1[tid]*rsqrtf(v+EPS);
        float o_ = bb1[tid] - m*s_;
        sc[tid]=s_; oc[tid]=o_;
        par[PF_S4+tid]=4.f*s_; par[PF_O4+tid]=4.f*o_;
    }
    __syncthreads();
    if(tid<24){ float a=b1[tid]; for(int c=0;c<8;c++) a += w1[tid*8+c]*oc[c]; par[PF_B1F+tid]=a; }
    if(tid<16){ par[PF_B2F+tid]=b2[tid]; }
    if(tid<11){ float a=b3[tid]; for(int c=0;c<8;c++) a += w3[tid*48+8+c]*oc[c]; par[PF_B3F+tid]=a; }
    if(tid<96){ int o=tid>>2, j=tid&3;
        paru[PU_W1+tid] = pk2u(w1[o*8+2*j]*sc[2*j], w1[o*8+2*j+1]*sc[2*j+1]); }
    if(tid<192){ int o=tid/12, j=tid-o*12;
        paru[PU_W2+tid] = pk2u(w2[o*24+2*j], w2[o*24+2*j+1]); }
    if(tid<44){ int o=tid>>2, j=tid&3; int c0=2*j, c1=2*j+1;
        float xa = w3[o*48+c0] + w3[o*48+8+c0]*sc[c0];
        float xb = w3[o*48+c1] + w3[o*48+8+c1]*sc[c1];
        paru[PU_W3X+tid] = pk2u(xa, xb);
        paru[PU_W3F+tid] = pk2u(w3[o*48+32+c0], w3[o*48+32+c1]);
        paru[PU_W3L+tid] = pk2u(w3[o*48+40+c0], w3[o*48+40+c1]);
    }
    if(tid<88){ int o=tid>>3, j=tid&7;
        paru[PU_W3FF+tid] = pk2u(w3[o*48+16+2*j], w3[o*48+16+2*j+1]); }
    if(tid<32){ int i=tid>>2, j=tid&3;
        paru[PU_A4+tid] = pk2u(4.f*A[i*8+2*j], 4.f*A[i*8+2*j+1]); }
}

// ---------------- K34: fused reservoir + FF + pre + BN2 partials (fdot2) ----------------
// grid: 8 bgroups(256 b) x 256 tgroups(4 t) = 2048 blocks -> 8 blocks/CU = 8 waves/SIMD
// (VGPR ~36 << 64 budget of launch_bounds(256,8)). Warm-up W=24: ||(4A)^24|| ~ 0.4^24*C
// (rho(4A)=0.4) -> negligible vs fp16 rounding; warm length never moved absmax (r1/r3/r5).
__global__ __launch_bounds__(256,8) void k34(
    const unsigned short* __restrict__ xT,
    float* __restrict__ ws, unsigned short* __restrict__ pws)
{
    const float* par = ws + PAR_OFF;
    const unsigned* pu = (const unsigned*)par;
    const int tid = threadIdx.x;
    const int b  = (blockIdx.x >> 8)*256 + tid;
    const int tg = blockIdx.x & 255;
    const int t0 = tg*4;
    const int tw = (t0 >= 24) ? (t0 - 24) : 0;
    const int tend = t0 + 4;

    h2 fh[4];
#pragma unroll
    for(int j=0;j<4;j++) fh[j] = pk(0.f, 0.f);
    float s1[11], s2[11];
#pragma unroll
    for(int o=0;o<11;o++){ s1[o]=0.f; s2[o]=0.f; }

    for(int t=tw; t<tend; t++){
        union { float4 v; unsigned u[4]; unsigned short us[8]; } ux;
        ux.v = *(const float4*)(xT + ((size_t)t*NB + b)*8);
        h2 xh[4];
#pragma unroll
        for(int j=0;j<4;j++) xh[j] = uph2(ux.u[j]);
        float nf[8];
#pragma unroll
        for(int i=0;i<8;i++){
            float acc = fmaf(par[PF_S4+i], h2f(ux.us[i]), par[PF_O4+i]);
#pragma unroll
            for(int j=0;j<4;j++) acc = fdot2(uph2(pu[PU_A4+i*4+j]), fh[j], acc);
            nf[i] = fminf(fmaxf(acc,-1.f),1.f);             // v_med3
        }
#pragma unroll
        for(int j=0;j<4;j++) fh[j] = pk(nf[2*j], nf[2*j+1]);
        if(t >= t0){                                         // uniform branch
            h2 lfh[4];
#pragma unroll
            for(int j=0;j<4;j++) lfh[j] = pk(leaky(nf[2*j]), leaky(nf[2*j+1]));
            h2 hh[12];
#pragma unroll
            for(int p=0;p<12;p++){
                float za = par[PF_B1F+2*p], zb = par[PF_B1F+2*p+1];
#pragma unroll
                for(int j=0;j<4;j++){
                    za = fdot2(uph2(pu[PU_W1+(2*p)*4+j]),   xh[j], za);
                    zb = fdot2(uph2(pu[PU_W1+(2*p+1)*4+j]), xh[j], zb);
                }
                hh[p] = pk(leaky(za), leaky(zb));
            }
            h2 ffh[8];
#pragma unroll
            for(int p=0;p<8;p++){
                float za = par[PF_B2F+2*p], zb = par[PF_B2F+2*p+1];
#pragma unroll
                for(int j=0;j<12;j++){
                    za = fdot2(uph2(pu[PU_W2+(2*p)*12+j]),   hh[j], za);
                    zb = fdot2(uph2(pu[PU_W2+(2*p+1)*12+j]), hh[j], zb);
                }
                ffh[p] = pk(leaky(za), leaky(zb));
            }
            const size_t base = (size_t)t*NB + b;
#pragma unroll
            for(int o=0;o<11;o++){
                float z = par[PF_B3F+o];
#pragma unroll
                for(int j=0;j<4;j++) z = fdot2(uph2(pu[PU_W3X+o*4+j]),  xh[j],  z);
#pragma unroll
                for(int j=0;j<4;j++) z = fdot2(uph2(pu[PU_W3F+o*4+j]),  fh[j],  z);
#pragma unroll
                for(int j=0;j<4;j++) z = fdot2(uph2(pu[PU_W3L+o*4+j]),  lfh[j], z);
#pragma unroll
                for(int j=0;j<8;j++) z = fdot2(uph2(pu[PU_W3FF+o*8+j]), ffh[j], z);
                s1[o] += z; s2[o] += z*z;
                pws[(size_t)o*TB + base] = f2h(z);           // per-o plane: coalesced
            }
        }
    }
    // BN2 partial reduction
#pragma unroll
    for(int o=0;o<11;o++){
#pragma unroll
        for(int m=32;m>=1;m>>=1){ s1[o]+=__shfl_xor(s1[o],m,64); s2[o]+=__shfl_xor(s2[o],m,64); }
    }
    __shared__ float red[4][22];
    const int wave=tid>>6, lane=tid&63;
    if(lane==0){
#pragma unroll
        for(int o=0;o<11;o++){ red[wave][o]=s1[o]; red[wave][11+o]=s2[o]; }
    }
    __syncthreads();
    if(tid<22){
        float tot = red[0][tid]+red[1][tid]+red[2][tid]+red[3][tid];
        atomicAdd(&ws[1024 + (blockIdx.x & 31)*32 + tid], tot);   // 32 slots x 32
    }
}

// ---------------- K6: BN2 finalize (inlined) + apply + leaky + t-mean ----------------
// grid: 11 o x 8 bg x 16 tg = 1408 blocks. Prologue: every block reduces the 32x22
// bn2 partials (coalesced, L2-hit) and computes al/be — kills the k5 launch.
__global__ __launch_bounds__(256) void k6(const float* __restrict__ ws,
                                          const unsigned short* __restrict__ pws,
                                          const float* __restrict__ g2, const float* __restrict__ bb2,
                                          float* __restrict__ out)
{
    __shared__ float red8[8][32];
    __shared__ float alv[11], bev[11];
    const int tid = threadIdx.x;
    {
        const int cnt = tid & 31, grp = tid >> 5;
        float s = 0.f;
#pragma unroll
        for(int i=0;i<4;i++) s += ws[1024 + (grp*4+i)*32 + cnt];
        red8[grp][cnt] = s;
    }
    __syncthreads();
    if(tid < 11){
        float sm = 0.f, sq = 0.f;
#pragma unroll
        for(int g=0; g<8; g++){ sm += red8[g][tid]; sq += red8[g][11+tid]; }
        const float inv = 1.0f/NELEM;
        float m = sm*inv;
        float v = sq*inv - m*m;
        float a = g2[tid]*rsqrtf(v+EPS);
        alv[tid] = a; bev[tid] = bb2[tid] - m*a;
    }
    __syncthreads();
    const int o  = blockIdx.x >> 7;
    const int r  = blockIdx.x & 127;
    const int bg = r & 7, tg = r >> 3;
    const int b  = bg*256 + tid;
    const float al = alv[o], be = bev[o];
    const unsigned short* pp = pws + (size_t)o*TB + b;
    float acc = 0.f;
#pragma unroll 4
    for(int i=0;i<64;i++){
        const int t = tg*64 + i;
        acc += leaky(fmaf(al, h2f(pp[(size_t)t*NB]), be));
    }
    atomicAdd(&out[b*11+o], acc*(1.0f/NT));
}

extern "C" void kernel_launch(void* const* d_in, const int* in_sizes, int n_in,
                              void* d_out, int out_size, void* d_ws, size_t ws_size,
                              hipStream_t stream)
{
    const float* x   = (const float*)d_in[0];
    const float* A   = (const float*)d_in[1];
    const float* g1  = (const float*)d_in[2];
    const float* bb1 = (const float*)d_in[3];
    const float* w1  = (const float*)d_in[4];
    const float* b1  = (const float*)d_in[5];
    const float* w2  = (const float*)d_in[6];
    const float* b2  = (const float*)d_in[7];
    const float* w3  = (const float*)d_in[8];
    const float* b3  = (const float*)d_in[9];
    const float* g2  = (const float*)d_in[10];
    const float* bb2 = (const float*)d_in[11];
    float* out = (float*)d_out;
    float* ws  = (float*)d_ws;
    unsigned short* xT  = (unsigned short*)((char*)d_ws + XT_BYTE);
    unsigned short* pws = (unsigned short*)((char*)d_ws + PWS_BYTE);

    (void)hipMemsetAsync(d_ws, 0, 40960, stream);                 // bn1/bn2 slots + params
    (void)hipMemsetAsync(d_out, 0, (size_t)out_size*4, stream);   // k6 accumulates atomically
    k0_tr  <<<2048, 256, 0, stream>>>(x, xT, ws);
    k2_fold<<<1,    256, 0, stream>>>(g1, bb1, w1, b1, w2, b2, w3, b3, A, ws);
    k34    <<<2048, 256, 0, stream>>>(xT, ws, pws);
    k6     <<<1408, 256, 0, stream>>>(ws, pws, g2, bb2, out);
}